// Round 4
// baseline (206.927 us; speedup 1.0000x reference)
//
#include <hip/hip_runtime.h>
#include <hip/hip_bf16.h>

#define NEMB 16
#define NHID 64

typedef short s16x8 __attribute__((ext_vector_type(8)));
typedef float f32x4 __attribute__((ext_vector_type(4)));

__device__ __forceinline__ unsigned int pack_bf16x2_rnd(float lo, float hi) {
    unsigned int ul = __float_as_uint(lo);
    unsigned int uh = __float_as_uint(hi);
    return ((ul + 0x8000u) >> 16) | ((uh + 0x8000u) & 0xffff0000u);
}
__device__ __forceinline__ unsigned int pack_bf16x2_trunc(float lo, float hi) {
    return (__float_as_uint(lo) >> 16) | (__float_as_uint(hi) & 0xffff0000u);
}

// Storage permutation: table slot t holds logical h1 index sigma(t).
//   sigma(t) = 32*((t>>5)&1) + 8*((t>>2)&3) + 4*((t>>4)&1) + (t&3)
// Chosen so that (a) per-(jb) 16-slot blocks are gather-contiguous and
// (b) the add-MFMA D-layout lands each lane with exactly the layer-2
// A-fragment elements it needs (no cross-lane repack).
#define SIGMA(t) (32 * (((t) >> 5) & 1) + 8 * (((t) >> 2) & 3) + 4 * (((t) >> 4) & 1) + ((t) & 3))

// ---------------------------------------------------------------------------
// Kernel P: per-node layer-1 partials, bf16, sigma-permuted storage order.
//   slot t of Htab[n] = emb[n] @ W1[0:16, sigma(t)] + b1[sigma(t)]
//   slot t of Btab[n] = emb[n] @ W1[16:32, sigma(t)]
// ---------------------------------------------------------------------------
__global__ __launch_bounds__(256) void precompute_h1_kernel(
        const float* __restrict__ emb,
        const float* __restrict__ W1, const float* __restrict__ b1,
        unsigned int* __restrict__ Htab, unsigned int* __restrict__ Btab,
        int nNodes) {
    __shared__ float sW1[32 * 64];
    __shared__ float sB1[64];
    for (int i = threadIdx.x; i < 2048; i += 256) sW1[i] = W1[i];
    if (threadIdx.x < 64) sB1[threadIdx.x] = b1[threadIdx.x];
    __syncthreads();

    int n = blockIdx.x * 256 + threadIdx.x;
    if (n >= nNodes) return;

    float e[16];
    const float4* pe = reinterpret_cast<const float4*>(emb + (size_t)n * NEMB);
#pragma unroll
    for (int q = 0; q < 4; ++q) {
        float4 v = pe[q];
        e[4 * q + 0] = v.x; e[4 * q + 1] = v.y;
        e[4 * q + 2] = v.z; e[4 * q + 3] = v.w;
    }

    unsigned int packT[32], packB[32];
#pragma unroll
    for (int p = 0; p < 32; ++p) {
        const int t = 2 * p;
        const int j0 = SIGMA(t);        // compile-time after unroll
        const int j1 = j0 + 1;          // sigma(t+1) == sigma(t)+1 for even t
        float t0 = sB1[j0], t1 = sB1[j1];
        float c0 = 0.0f, c1 = 0.0f;
#pragma unroll
        for (int k = 0; k < 16; ++k) {
            t0 = fmaf(e[k], sW1[k * 64 + j0], t0);
            t1 = fmaf(e[k], sW1[k * 64 + j1], t1);
            c0 = fmaf(e[k], sW1[(16 + k) * 64 + j0], c0);
            c1 = fmaf(e[k], sW1[(16 + k) * 64 + j1], c1);
        }
        packT[p] = pack_bf16x2_rnd(t0, t1);
        packB[p] = pack_bf16x2_rnd(c0, c1);
    }

    uint4* ot = reinterpret_cast<uint4*>(Htab + (size_t)n * 32);
    uint4* ob = reinterpret_cast<uint4*>(Btab + (size_t)n * 32);
#pragma unroll
    for (int q = 0; q < 8; ++q) {
        ot[q] = make_uint4(packT[4 * q + 0], packT[4 * q + 1], packT[4 * q + 2], packT[4 * q + 3]);
        ob[q] = make_uint4(packB[4 * q + 0], packB[4 * q + 1], packB[4 * q + 2], packB[4 * q + 3]);
    }
}

// ---------------------------------------------------------------------------
// Kernel E: 16 edges per wave-iter.
//  Phase 1 (add-MFMA, jb=0..3): D_jb[row][e] = Htab[s_e][jb*16+row] + Btab[d_e][jb*16+row]
//     A = identity placement (A[row][k] = 1.0 iff (k&15)==row), B = gathered bf16.
//     Lane l gathers: table = (lc>>1 ? Btab : Htab), half = lc&1,
//     4 x dwordx4 at slot offsets jb*16 + half*8.
//  Phase 2: relu + truncate-pack -> layer-2 A-frags (lane-local by construction).
//  Phase 3: layer-2 MFMA vs W2 frags; epilogue = bias/relu/W3 dot + 16-lane reduce.
// ---------------------------------------------------------------------------
#define EDGES_PER_ITER 64   // per block (4 waves x 16 edges)
#define ITERS 8             // 512 edges per block

__global__ __launch_bounds__(256) void edge_mfma2_kernel(
        const unsigned short* __restrict__ Htab,
        const unsigned short* __restrict__ Btab,
        const int* __restrict__ ei,
        const float* __restrict__ W2, const float* __restrict__ b2,
        const float* __restrict__ W3, const float* __restrict__ b3,
        float* __restrict__ out, int nE) {
    const int tid = threadIdx.x;
    const int w  = tid >> 6;       // wave id 0..3
    const int l  = tid & 63;       // lane
    const int lr = l & 15;         // edge slot / B col
    const int lc = l >> 4;         // k-chunk group 0..3
    const int half = lc & 1;       // which 8-slot half
    const int tab  = lc >> 1;      // 0 = Htab (src), 1 = Btab (dst)

    // --- identity A-fragment for the add-MFMA (one 1.0 per lane at most) ---
    union { unsigned short s[8]; s16x8 v; } aid;
    {
        int row = lr;
        int tgt = ((row >> 3) == half) ? (row & 7) : -1;
#pragma unroll
        for (int i = 0; i < 8; ++i)
            aid.s[i] = (i == tgt) ? (unsigned short)0x3F80 : (unsigned short)0;
    }

    // --- W2 B-fragments in registers (one-time) ---
    s16x8 Bf[2][2];  // [ntile][khalf]
#pragma unroll
    for (int t = 0; t < 2; ++t) {
#pragma unroll
        for (int h = 0; h < 2; ++h) {
            s16x8 f;
#pragma unroll
            for (int i = 0; i < 8; ++i) {
                int k = h * 32 + lc * 8 + i;
                int n = t * 16 + lr;
                float v = W2[k * 32 + n];
                f[i] = (short)((__float_as_uint(v) + 0x8000u) >> 16);
            }
            Bf[t][h] = f;
        }
    }
    const float b2v0 = b2[lr], b2v1 = b2[16 + lr];
    const float w3v0 = W3[lr], w3v1 = W3[16 + lr];
    const float b3v = b3[0];

    const unsigned short* tabbase = tab ? Btab : Htab;
    const int* eibase = ei + (tab ? nE : 0);

#pragma unroll 1
    for (int it = 0; it < ITERS; ++it) {
        int eb = blockIdx.x * (EDGES_PER_ITER * ITERS) + it * EDGES_PER_ITER + w * 16;
        if (eb >= nE) break;
        int e = eb + lr;
        int ec = e < nE ? e : (nE - 1);
        int idx = eibase[ec];

        const unsigned short* base = tabbase + (size_t)idx * 64 + half * 8;
        uint4 q0 = *reinterpret_cast<const uint4*>(base +  0);
        uint4 q1 = *reinterpret_cast<const uint4*>(base + 16);
        uint4 q2 = *reinterpret_cast<const uint4*>(base + 32);
        uint4 q3 = *reinterpret_cast<const uint4*>(base + 48);

        union { uint4 q; s16x8 v; } d0, d1, d2, d3;
        d0.q = q0; d1.q = q1; d2.q = q2; d3.q = q3;

        f32x4 s0 = {0.f, 0.f, 0.f, 0.f};
        f32x4 s1 = {0.f, 0.f, 0.f, 0.f};
        f32x4 s2 = {0.f, 0.f, 0.f, 0.f};
        f32x4 s3 = {0.f, 0.f, 0.f, 0.f};
        s0 = __builtin_amdgcn_mfma_f32_16x16x32_bf16(aid.v, d0.v, s0, 0, 0, 0);
        s1 = __builtin_amdgcn_mfma_f32_16x16x32_bf16(aid.v, d1.v, s1, 0, 0, 0);
        s2 = __builtin_amdgcn_mfma_f32_16x16x32_bf16(aid.v, d2.v, s2, 0, 0, 0);
        s3 = __builtin_amdgcn_mfma_f32_16x16x32_bf16(aid.v, d3.v, s3, 0, 0, 0);

        // relu + truncate-pack directly into layer-2 A-fragments.
        // Lane holds h1[e=lr][j = 8*lc + r + 4*(jb&1) + 32*(jb>>1)]:
        //   A0 elem i (j = 8*lc+i): i=0..3 <- s0[r], i=4..7 <- s1[r]
        //   A1 elem i (j = 32+8*lc+i): from s2, s3
        union { unsigned int u[4]; s16x8 v; } a0, a1;
        a0.u[0] = pack_bf16x2_trunc(fmaxf(s0[0], 0.f), fmaxf(s0[1], 0.f));
        a0.u[1] = pack_bf16x2_trunc(fmaxf(s0[2], 0.f), fmaxf(s0[3], 0.f));
        a0.u[2] = pack_bf16x2_trunc(fmaxf(s1[0], 0.f), fmaxf(s1[1], 0.f));
        a0.u[3] = pack_bf16x2_trunc(fmaxf(s1[2], 0.f), fmaxf(s1[3], 0.f));
        a1.u[0] = pack_bf16x2_trunc(fmaxf(s2[0], 0.f), fmaxf(s2[1], 0.f));
        a1.u[1] = pack_bf16x2_trunc(fmaxf(s2[2], 0.f), fmaxf(s2[3], 0.f));
        a1.u[2] = pack_bf16x2_trunc(fmaxf(s3[0], 0.f), fmaxf(s3[1], 0.f));
        a1.u[3] = pack_bf16x2_trunc(fmaxf(s3[2], 0.f), fmaxf(s3[3], 0.f));

        f32x4 acc0 = {0.f, 0.f, 0.f, 0.f};
        f32x4 acc1 = {0.f, 0.f, 0.f, 0.f};
        acc0 = __builtin_amdgcn_mfma_f32_16x16x32_bf16(a0.v, Bf[0][0], acc0, 0, 0, 0);
        acc0 = __builtin_amdgcn_mfma_f32_16x16x32_bf16(a1.v, Bf[0][1], acc0, 0, 0, 0);
        acc1 = __builtin_amdgcn_mfma_f32_16x16x32_bf16(a0.v, Bf[1][0], acc1, 0, 0, 0);
        acc1 = __builtin_amdgcn_mfma_f32_16x16x32_bf16(a1.v, Bf[1][1], acc1, 0, 0, 0);

        // Layer 3 + reduce over the 16-lane col group.
        float v0, v1, v2, v3;
        {
            float h2a, h2b;
            h2a = fmaxf(acc0[0] + b2v0, 0.f); h2b = fmaxf(acc1[0] + b2v1, 0.f);
            v0 = h2a * w3v0 + h2b * w3v1;
            h2a = fmaxf(acc0[1] + b2v0, 0.f); h2b = fmaxf(acc1[1] + b2v1, 0.f);
            v1 = h2a * w3v0 + h2b * w3v1;
            h2a = fmaxf(acc0[2] + b2v0, 0.f); h2b = fmaxf(acc1[2] + b2v1, 0.f);
            v2 = h2a * w3v0 + h2b * w3v1;
            h2a = fmaxf(acc0[3] + b2v0, 0.f); h2b = fmaxf(acc1[3] + b2v1, 0.f);
            v3 = h2a * w3v0 + h2b * w3v1;
        }
#pragma unroll
        for (int m = 1; m < 16; m <<= 1) {
            v0 += __shfl_xor(v0, m);
            v1 += __shfl_xor(v1, m);
            v2 += __shfl_xor(v2, m);
            v3 += __shfl_xor(v3, m);
        }

        if (lr == 0) {
            float4 o;
            o.x = 1.0f / (1.0f + __expf(-(v0 + b3v)));
            o.y = 1.0f / (1.0f + __expf(-(v1 + b3v)));
            o.z = 1.0f / (1.0f + __expf(-(v2 + b3v)));
            o.w = 1.0f / (1.0f + __expf(-(v3 + b3v)));
            int basee = eb + lc * 4;   // rows lc*4 .. lc*4+3
            if (basee + 4 <= nE) {
                *reinterpret_cast<float4*>(out + basee) = o;
            } else {
                float ov[4] = {o.x, o.y, o.z, o.w};
                for (int r = 0; r < 4; ++r)
                    if (basee + r < nE) out[basee + r] = ov[r];
            }
        }
    }
}

// ---------------------------------------------------------------------------
// Fallback: per-edge full MLP (no workspace), f32 output.
// ---------------------------------------------------------------------------
__global__ __launch_bounds__(256) void edge_mlp_naive_kernel(
        const float* __restrict__ emb, const int* __restrict__ ei,
        const float* __restrict__ W1, const float* __restrict__ b1,
        const float* __restrict__ W2, const float* __restrict__ b2,
        const float* __restrict__ W3, const float* __restrict__ b3,
        float* __restrict__ out, int nE) {
    __shared__ __align__(16) float sW1[32 * 64];
    __shared__ __align__(16) float sW2[64 * 32];
    __shared__ float sW3[32];
    __shared__ float sB1[64];
    __shared__ float sB2[32];
    __shared__ float sB3;
    for (int i = threadIdx.x; i < 2048; i += 256) {
        sW1[i] = W1[i];
        sW2[i] = W2[i];
    }
    if (threadIdx.x < 64) sB1[threadIdx.x] = b1[threadIdx.x];
    if (threadIdx.x < 32) {
        sW3[threadIdx.x] = W3[threadIdx.x];
        sB2[threadIdx.x] = b2[threadIdx.x];
    }
    if (threadIdx.x == 0) sB3 = b3[0];
    __syncthreads();

    int e = blockIdx.x * 256 + threadIdx.x;
    if (e >= nE) return;

    int s = ei[e];
    int d = ei[nE + e];

    float f[32];
    const float4* ps = reinterpret_cast<const float4*>(emb + (size_t)s * NEMB);
    const float4* pd = reinterpret_cast<const float4*>(emb + (size_t)d * NEMB);
#pragma unroll
    for (int q = 0; q < 4; ++q) {
        float4 v = ps[q];
        f[4 * q + 0] = v.x; f[4 * q + 1] = v.y; f[4 * q + 2] = v.z; f[4 * q + 3] = v.w;
    }
#pragma unroll
    for (int q = 0; q < 4; ++q) {
        float4 v = pd[q];
        f[16 + 4 * q + 0] = v.x; f[16 + 4 * q + 1] = v.y;
        f[16 + 4 * q + 2] = v.z; f[16 + 4 * q + 3] = v.w;
    }

    float h1[64];
#pragma unroll
    for (int j = 0; j < 64; j += 4) {
        float a0 = sB1[j + 0], a1 = sB1[j + 1], a2 = sB1[j + 2], a3 = sB1[j + 3];
#pragma unroll
        for (int k = 0; k < 32; ++k) {
            float4 wv = *reinterpret_cast<const float4*>(sW1 + k * 64 + j);
            a0 = fmaf(f[k], wv.x, a0);
            a1 = fmaf(f[k], wv.y, a1);
            a2 = fmaf(f[k], wv.z, a2);
            a3 = fmaf(f[k], wv.w, a3);
        }
        h1[j + 0] = fmaxf(a0, 0.0f);
        h1[j + 1] = fmaxf(a1, 0.0f);
        h1[j + 2] = fmaxf(a2, 0.0f);
        h1[j + 3] = fmaxf(a3, 0.0f);
    }

    float acc = sB3;
#pragma unroll
    for (int j = 0; j < 32; j += 4) {
        float a0 = sB2[j + 0], a1 = sB2[j + 1], a2 = sB2[j + 2], a3 = sB2[j + 3];
#pragma unroll
        for (int k = 0; k < 64; ++k) {
            float4 wv = *reinterpret_cast<const float4*>(sW2 + k * 32 + j);
            a0 = fmaf(h1[k], wv.x, a0);
            a1 = fmaf(h1[k], wv.y, a1);
            a2 = fmaf(h1[k], wv.z, a2);
            a3 = fmaf(h1[k], wv.w, a3);
        }
        acc = fmaf(fmaxf(a0, 0.0f), sW3[j + 0], acc);
        acc = fmaf(fmaxf(a1, 0.0f), sW3[j + 1], acc);
        acc = fmaf(fmaxf(a2, 0.0f), sW3[j + 2], acc);
        acc = fmaf(fmaxf(a3, 0.0f), sW3[j + 3], acc);
    }

    out[e] = 1.0f / (1.0f + __expf(-acc));
}

// ---------------------------------------------------------------------------
// Kernel A: edge_index (int32) -> float32 copy into out[E .. 3E)
// ---------------------------------------------------------------------------
__global__ __launch_bounds__(256) void edge_idx_copy_kernel(
        const int* __restrict__ ei, float* __restrict__ out, int n) {
    int i = (blockIdx.x * 256 + threadIdx.x) * 4;
    if (i + 4 <= n) {
        int4 a = *reinterpret_cast<const int4*>(ei + i);
        float4 r = make_float4((float)a.x, (float)a.y, (float)a.z, (float)a.w);
        *reinterpret_cast<float4*>(out + i) = r;
    } else {
        for (; i < n; ++i) out[i] = (float)ei[i];
    }
}

extern "C" void kernel_launch(void* const* d_in, const int* in_sizes, int n_in,
                              void* d_out, int out_size, void* d_ws, size_t ws_size,
                              hipStream_t stream) {
    const float* emb = (const float*)d_in[0];
    const int*   ei  = (const int*)d_in[1];
    const float* W1  = (const float*)d_in[2];
    const float* b1  = (const float*)d_in[3];
    const float* W2  = (const float*)d_in[4];
    const float* b2  = (const float*)d_in[5];
    const float* W3  = (const float*)d_in[6];
    const float* b3  = (const float*)d_in[7];

    const int nNodes = in_sizes[0] / NEMB;   // 100000
    const int n2E    = in_sizes[1];          // 2 * E
    const int nE     = n2E / 2;              // E

    float* out = (float*)d_out;  // f32: [E probs][2E edge indices]

    const size_t tbl_bytes = (size_t)nNodes * 64 * sizeof(unsigned short);  // 12.8 MB
    const bool use_ws = (ws_size >= 2 * tbl_bytes);

    if (use_ws) {
        unsigned int* Htab = (unsigned int*)d_ws;
        unsigned int* Btab = Htab + (size_t)nNodes * 32;

        precompute_h1_kernel<<<(nNodes + 255) / 256, 256, 0, stream>>>(
            emb, W1, b1, Htab, Btab, nNodes);

        const int epb = EDGES_PER_ITER * ITERS;  // 512
        edge_mfma2_kernel<<<(nE + epb - 1) / epb, 256, 0, stream>>>(
            (const unsigned short*)Htab, (const unsigned short*)Btab, ei,
            W2, b2, W3, b3, out, nE);
    } else {
        edge_mlp_naive_kernel<<<(nE + 255) / 256, 256, 0, stream>>>(
            emb, ei, W1, b1, W2, b2, W3, b3, out, nE);
    }

    edge_idx_copy_kernel<<<((n2E + 3) / 4 + 255) / 256, 256, 0, stream>>>(
        ei, out + nE, n2E);
}

// Round 5
// 192.767 us; speedup vs baseline: 1.0735x; 1.0735x over previous
//
#include <hip/hip_runtime.h>
#include <hip/hip_bf16.h>

#define NEMB 16

typedef short s16x8 __attribute__((ext_vector_type(8)));
typedef float f32x16 __attribute__((ext_vector_type(16)));

__device__ __forceinline__ unsigned int pack_bf16x2_rnd(float lo, float hi) {
    unsigned int ul = __float_as_uint(lo);
    unsigned int uh = __float_as_uint(hi);
    return ((ul + 0x8000u) >> 16) | ((uh + 0x8000u) & 0xffff0000u);
}

// ---------------------------------------------------------------------------
// Kernel P: per-node layer-1 partials, bf16, natural j order (0..63).
//   Htab[n][j] = emb[n] @ W1[0:16, j] + b1[j]
//   Btab[n][j] = emb[n] @ W1[16:32, j]
// ---------------------------------------------------------------------------
__global__ __launch_bounds__(256) void precompute_h1_kernel(
        const float* __restrict__ emb,
        const float* __restrict__ W1, const float* __restrict__ b1,
        unsigned int* __restrict__ Htab, unsigned int* __restrict__ Btab,
        int nNodes) {
    __shared__ float sW1[32 * 64];
    __shared__ float sB1[64];
    for (int i = threadIdx.x; i < 2048; i += 256) sW1[i] = W1[i];
    if (threadIdx.x < 64) sB1[threadIdx.x] = b1[threadIdx.x];
    __syncthreads();

    int n = blockIdx.x * 256 + threadIdx.x;
    if (n >= nNodes) return;

    float e[16];
    const float4* pe = reinterpret_cast<const float4*>(emb + (size_t)n * NEMB);
#pragma unroll
    for (int q = 0; q < 4; ++q) {
        float4 v = pe[q];
        e[4 * q + 0] = v.x; e[4 * q + 1] = v.y;
        e[4 * q + 2] = v.z; e[4 * q + 3] = v.w;
    }

    unsigned int packT[32], packB[32];
#pragma unroll
    for (int j = 0; j < 64; j += 2) {
        float t0 = sB1[j], t1 = sB1[j + 1];
        float c0 = 0.0f, c1 = 0.0f;
#pragma unroll
        for (int k = 0; k < 16; ++k) {
            t0 = fmaf(e[k], sW1[k * 64 + j + 0], t0);
            t1 = fmaf(e[k], sW1[k * 64 + j + 1], t1);
            c0 = fmaf(e[k], sW1[(16 + k) * 64 + j + 0], c0);
            c1 = fmaf(e[k], sW1[(16 + k) * 64 + j + 1], c1);
        }
        packT[j / 2] = pack_bf16x2_rnd(t0, t1);
        packB[j / 2] = pack_bf16x2_rnd(c0, c1);
    }

    uint4* ot = reinterpret_cast<uint4*>(Htab + (size_t)n * 32);
    uint4* ob = reinterpret_cast<uint4*>(Btab + (size_t)n * 32);
#pragma unroll
    for (int q = 0; q < 8; ++q) {
        ot[q] = make_uint4(packT[4 * q + 0], packT[4 * q + 1], packT[4 * q + 2], packT[4 * q + 3]);
        ob[q] = make_uint4(packB[4 * q + 0], packB[4 * q + 1], packB[4 * q + 2], packB[4 * q + 3]);
    }
}

// ---------------------------------------------------------------------------
// Kernel E: 32 edges per wave-iter via swapped-operand 32x32x16 MFMA.
//   D[n][e] = sum_k W2T[n][k] * h1T[k][e]   (4 MFMAs over K=64, C init = b2)
//   A-frag (static): lane l holds W2[f*16 + (l>>5)*8 + i][l&31]
//   B-frag (built):  lane l holds h1[edge=l&31][j = f*16 + (l>>5)*8 + i]
//     built from 2x16B gathers per frag: relu(Htab[s][j] + Btab[d][j]).
//   D-layout (m101): col=lane&31=edge, row n=(reg&3)+8*(reg>>2)+4*(lane>>5).
//   Layer-3: per-lane 16-term dot + ONE shfl_xor(32); sigmoid wave-uniform.
//   Edge-index f32 copy is fused (s from hi=0 lanes, d from hi=1 lanes).
// ---------------------------------------------------------------------------
#define WAVES 4
#define ITERS 8
#define EDGES_PER_BLOCK (WAVES * 32 * ITERS)   // 1024

__global__ __launch_bounds__(256) void edge_mfma32_kernel(
        const unsigned short* __restrict__ Htab,
        const unsigned short* __restrict__ Btab,
        const int* __restrict__ ei,
        const float* __restrict__ W2, const float* __restrict__ b2,
        const float* __restrict__ W3, const float* __restrict__ b3,
        float* __restrict__ out, int nE) {
    const int tid = threadIdx.x;
    const int w  = tid >> 6;       // wave id 0..3
    const int l  = tid & 63;       // lane
    const int el = l & 31;         // edge slot (B col / D col)
    const int hi = l >> 5;         // k-group / n-group select

    // --- Static A-frags: W2^T, rounded to bf16 (once per block) ---
    s16x8 Af[4];
#pragma unroll
    for (int f = 0; f < 4; ++f) {
        s16x8 a;
#pragma unroll
        for (int i = 0; i < 8; ++i) {
            float v = W2[(f * 16 + hi * 8 + i) * 32 + el];
            a[i] = (short)((__float_as_uint(v) + 0x8000u) >> 16);
        }
        Af[f] = a;
    }
    // --- Per-lane epilogue constants: n(reg) = (reg&3) + 8*(reg>>2) + 4*hi ---
    float b2i[16], w3v[16];
#pragma unroll
    for (int r = 0; r < 16; ++r) {
        int n = (r & 3) + 8 * (r >> 2) + 4 * hi;
        b2i[r] = b2[n];
        w3v[r] = W3[n];
    }
    const float b3v = b3[0];

#pragma unroll 1
    for (int it = 0; it < ITERS; ++it) {
        int eb = blockIdx.x * EDGES_PER_BLOCK + it * (WAVES * 32) + w * 32;
        if (eb >= nE) break;
        int e  = eb + el;
        int ec = e < nE ? e : (nE - 1);
        int s = ei[ec];
        int d = ei[nE + ec];

        const unsigned short* ph = Htab + ((size_t)s << 6) + (hi << 3);
        const unsigned short* pb = Btab + ((size_t)d << 6) + (hi << 3);

        // issue all 8 gathers up front (independent 16B loads)
        uint4 hq0 = *reinterpret_cast<const uint4*>(ph +  0);
        uint4 hq1 = *reinterpret_cast<const uint4*>(ph + 16);
        uint4 hq2 = *reinterpret_cast<const uint4*>(ph + 32);
        uint4 hq3 = *reinterpret_cast<const uint4*>(ph + 48);
        uint4 bq0 = *reinterpret_cast<const uint4*>(pb +  0);
        uint4 bq1 = *reinterpret_cast<const uint4*>(pb + 16);
        uint4 bq2 = *reinterpret_cast<const uint4*>(pb + 32);
        uint4 bq3 = *reinterpret_cast<const uint4*>(pb + 48);

        f32x16 acc;
#pragma unroll
        for (int r = 0; r < 16; ++r) acc[r] = b2i[r];

        uint4 hqs[4] = {hq0, hq1, hq2, hq3};
        uint4 bqs[4] = {bq0, bq1, bq2, bq3};
#pragma unroll
        for (int f = 0; f < 4; ++f) {
            unsigned int hu[4] = {hqs[f].x, hqs[f].y, hqs[f].z, hqs[f].w};
            unsigned int bu[4] = {bqs[f].x, bqs[f].y, bqs[f].z, bqs[f].w};
            union { unsigned int u[4]; s16x8 v; } bf;
#pragma unroll
            for (int q = 0; q < 4; ++q) {
                float lo = __uint_as_float(hu[q] << 16) +
                           __uint_as_float(bu[q] << 16);
                float hi2 = __uint_as_float(hu[q] & 0xffff0000u) +
                            __uint_as_float(bu[q] & 0xffff0000u);
                lo  = fmaxf(lo, 0.0f);
                hi2 = fmaxf(hi2, 0.0f);
                // truncate-pack [bf16(lo), bf16(hi2)] in one v_perm_b32
                bf.u[q] = __builtin_amdgcn_perm(__float_as_uint(hi2),
                                                __float_as_uint(lo),
                                                0x07060302u);
            }
            acc = __builtin_amdgcn_mfma_f32_32x32x16_bf16(Af[f], bf.v, acc, 0, 0, 0);
        }

        // Layer 3: per-lane 16-term dot over its n's, then one cross-half add.
        float v = 0.0f;
#pragma unroll
        for (int r = 0; r < 16; ++r)
            v = fmaf(fmaxf(acc[r], 0.0f), w3v[r], v);
        v += __shfl_xor(v, 32);

        float p = 1.0f / (1.0f + __expf(-(v + b3v)));

        if (e < nE) {
            if (hi == 0) {
                out[e] = p;                              // probs
                out[nE + e] = (float)s;                  // edge_index row 0
            } else {
                out[(size_t)2 * nE + e] = (float)d;      // edge_index row 1
            }
        }
    }
}

// ---------------------------------------------------------------------------
// Fallback: per-edge full MLP (no workspace), f32 output.
// ---------------------------------------------------------------------------
__global__ __launch_bounds__(256) void edge_mlp_naive_kernel(
        const float* __restrict__ emb, const int* __restrict__ ei,
        const float* __restrict__ W1, const float* __restrict__ b1,
        const float* __restrict__ W2, const float* __restrict__ b2,
        const float* __restrict__ W3, const float* __restrict__ b3,
        float* __restrict__ out, int nE) {
    __shared__ __align__(16) float sW1[32 * 64];
    __shared__ __align__(16) float sW2[64 * 32];
    __shared__ float sW3[32];
    __shared__ float sB1[64];
    __shared__ float sB2[32];
    __shared__ float sB3;
    for (int i = threadIdx.x; i < 2048; i += 256) {
        sW1[i] = W1[i];
        sW2[i] = W2[i];
    }
    if (threadIdx.x < 64) sB1[threadIdx.x] = b1[threadIdx.x];
    if (threadIdx.x < 32) {
        sW3[threadIdx.x] = W3[threadIdx.x];
        sB2[threadIdx.x] = b2[threadIdx.x];
    }
    if (threadIdx.x == 0) sB3 = b3[0];
    __syncthreads();

    int e = blockIdx.x * 256 + threadIdx.x;
    if (e >= nE) return;

    int s = ei[e];
    int d = ei[nE + e];

    float f[32];
    const float4* ps = reinterpret_cast<const float4*>(emb + (size_t)s * NEMB);
    const float4* pd = reinterpret_cast<const float4*>(emb + (size_t)d * NEMB);
#pragma unroll
    for (int q = 0; q < 4; ++q) {
        float4 v = ps[q];
        f[4 * q + 0] = v.x; f[4 * q + 1] = v.y; f[4 * q + 2] = v.z; f[4 * q + 3] = v.w;
    }
#pragma unroll
    for (int q = 0; q < 4; ++q) {
        float4 v = pd[q];
        f[16 + 4 * q + 0] = v.x; f[16 + 4 * q + 1] = v.y;
        f[16 + 4 * q + 2] = v.z; f[16 + 4 * q + 3] = v.w;
    }

    float h1[64];
#pragma unroll
    for (int j = 0; j < 64; j += 4) {
        float a0 = sB1[j + 0], a1 = sB1[j + 1], a2 = sB1[j + 2], a3 = sB1[j + 3];
#pragma unroll
        for (int k = 0; k < 32; ++k) {
            float4 wv = *reinterpret_cast<const float4*>(sW1 + k * 64 + j);
            a0 = fmaf(f[k], wv.x, a0);
            a1 = fmaf(f[k], wv.y, a1);
            a2 = fmaf(f[k], wv.z, a2);
            a3 = fmaf(f[k], wv.w, a3);
        }
        h1[j + 0] = fmaxf(a0, 0.0f);
        h1[j + 1] = fmaxf(a1, 0.0f);
        h1[j + 2] = fmaxf(a2, 0.0f);
        h1[j + 3] = fmaxf(a3, 0.0f);
    }

    float acc = sB3;
#pragma unroll
    for (int j = 0; j < 32; j += 4) {
        float a0 = sB2[j + 0], a1 = sB2[j + 1], a2 = sB2[j + 2], a3 = sB2[j + 3];
#pragma unroll
        for (int k = 0; k < 64; ++k) {
            float4 wv = *reinterpret_cast<const float4*>(sW2 + k * 32 + j);
            a0 = fmaf(h1[k], wv.x, a0);
            a1 = fmaf(h1[k], wv.y, a1);
            a2 = fmaf(h1[k], wv.z, a2);
            a3 = fmaf(h1[k], wv.w, a3);
        }
        acc = fmaf(fmaxf(a0, 0.0f), sW3[j + 0], acc);
        acc = fmaf(fmaxf(a1, 0.0f), sW3[j + 1], acc);
        acc = fmaf(fmaxf(a2, 0.0f), sW3[j + 2], acc);
        acc = fmaf(fmaxf(a3, 0.0f), sW3[j + 3], acc);
    }

    out[e] = 1.0f / (1.0f + __expf(-acc));
}

// ---------------------------------------------------------------------------
// Kernel A (fallback path only): edge_index (int32) -> f32 copy into out[E..3E)
// ---------------------------------------------------------------------------
__global__ __launch_bounds__(256) void edge_idx_copy_kernel(
        const int* __restrict__ ei, float* __restrict__ out, int n) {
    int i = (blockIdx.x * 256 + threadIdx.x) * 4;
    if (i + 4 <= n) {
        int4 a = *reinterpret_cast<const int4*>(ei + i);
        float4 r = make_float4((float)a.x, (float)a.y, (float)a.z, (float)a.w);
        *reinterpret_cast<float4*>(out + i) = r;
    } else {
        for (; i < n; ++i) out[i] = (float)ei[i];
    }
}

extern "C" void kernel_launch(void* const* d_in, const int* in_sizes, int n_in,
                              void* d_out, int out_size, void* d_ws, size_t ws_size,
                              hipStream_t stream) {
    const float* emb = (const float*)d_in[0];
    const int*   ei  = (const int*)d_in[1];
    const float* W1  = (const float*)d_in[2];
    const float* b1  = (const float*)d_in[3];
    const float* W2  = (const float*)d_in[4];
    const float* b2  = (const float*)d_in[5];
    const float* W3  = (const float*)d_in[6];
    const float* b3  = (const float*)d_in[7];

    const int nNodes = in_sizes[0] / NEMB;   // 100000
    const int n2E    = in_sizes[1];          // 2 * E
    const int nE     = n2E / 2;              // E

    float* out = (float*)d_out;  // f32: [E probs][2E edge indices]

    const size_t tbl_bytes = (size_t)nNodes * 64 * sizeof(unsigned short);  // 12.8 MB
    const bool use_ws = (ws_size >= 2 * tbl_bytes);

    if (use_ws) {
        unsigned int* Htab = (unsigned int*)d_ws;
        unsigned int* Btab = Htab + (size_t)nNodes * 32;

        precompute_h1_kernel<<<(nNodes + 255) / 256, 256, 0, stream>>>(
            emb, W1, b1, Htab, Btab, nNodes);

        edge_mfma32_kernel<<<(nE + EDGES_PER_BLOCK - 1) / EDGES_PER_BLOCK, 256, 0,
                             stream>>>(
            (const unsigned short*)Htab, (const unsigned short*)Btab, ei,
            W2, b2, W3, b3, out, nE);
        // edge-index copy fused into edge_mfma32_kernel
    } else {
        edge_mlp_naive_kernel<<<(nE + 255) / 256, 256, 0, stream>>>(
            emb, ei, W1, b1, W2, b2, W3, b3, out, nE);
        edge_idx_copy_kernel<<<((n2E + 3) / 4 + 255) / 256, 256, 0, stream>>>(
            ei, out + nE, n2E);
    }
}

// Round 6
// 180.813 us; speedup vs baseline: 1.1444x; 1.0661x over previous
//
#include <hip/hip_runtime.h>
#include <hip/hip_bf16.h>

#define NEMB 16

typedef short s16x8 __attribute__((ext_vector_type(8)));
typedef float f32x16 __attribute__((ext_vector_type(16)));

__device__ __forceinline__ unsigned int pack_bf16x2_rnd(float lo, float hi) {
    unsigned int ul = __float_as_uint(lo);
    unsigned int uh = __float_as_uint(hi);
    return ((ul + 0x8000u) >> 16) | ((uh + 0x8000u) & 0xffff0000u);
}

// ---------------------------------------------------------------------------
// Kernel P: per-node layer-1 partials, bf16, natural j order (0..63).
//   Htab[n][j] = emb[n] @ W1[0:16, j] + b1[j]
//   Btab[n][j] = emb[n] @ W1[16:32, j]
// ---------------------------------------------------------------------------
__global__ __launch_bounds__(256) void precompute_h1_kernel(
        const float* __restrict__ emb,
        const float* __restrict__ W1, const float* __restrict__ b1,
        unsigned int* __restrict__ Htab, unsigned int* __restrict__ Btab,
        int nNodes) {
    __shared__ float sW1[32 * 64];
    __shared__ float sB1[64];
    for (int i = threadIdx.x; i < 2048; i += 256) sW1[i] = W1[i];
    if (threadIdx.x < 64) sB1[threadIdx.x] = b1[threadIdx.x];
    __syncthreads();

    int n = blockIdx.x * 256 + threadIdx.x;
    if (n >= nNodes) return;

    float e[16];
    const float4* pe = reinterpret_cast<const float4*>(emb + (size_t)n * NEMB);
#pragma unroll
    for (int q = 0; q < 4; ++q) {
        float4 v = pe[q];
        e[4 * q + 0] = v.x; e[4 * q + 1] = v.y;
        e[4 * q + 2] = v.z; e[4 * q + 3] = v.w;
    }

    unsigned int packT[32], packB[32];
#pragma unroll
    for (int j = 0; j < 64; j += 2) {
        float t0 = sB1[j], t1 = sB1[j + 1];
        float c0 = 0.0f, c1 = 0.0f;
#pragma unroll
        for (int k = 0; k < 16; ++k) {
            t0 = fmaf(e[k], sW1[k * 64 + j + 0], t0);
            t1 = fmaf(e[k], sW1[k * 64 + j + 1], t1);
            c0 = fmaf(e[k], sW1[(16 + k) * 64 + j + 0], c0);
            c1 = fmaf(e[k], sW1[(16 + k) * 64 + j + 1], c1);
        }
        packT[j / 2] = pack_bf16x2_rnd(t0, t1);
        packB[j / 2] = pack_bf16x2_rnd(c0, c1);
    }

    uint4* ot = reinterpret_cast<uint4*>(Htab + (size_t)n * 32);
    uint4* ob = reinterpret_cast<uint4*>(Btab + (size_t)n * 32);
#pragma unroll
    for (int q = 0; q < 8; ++q) {
        ot[q] = make_uint4(packT[4 * q + 0], packT[4 * q + 1], packT[4 * q + 2], packT[4 * q + 3]);
        ob[q] = make_uint4(packB[4 * q + 0], packB[4 * q + 1], packB[4 * q + 2], packB[4 * q + 3]);
    }
}

// ---------------------------------------------------------------------------
// Kernel E: 32 edges/wave-iter via swapped-operand 32x32x16 MFMA, software-
// pipelined: all ei loads hoisted to the prologue; table gathers double-
// buffered one iteration ahead (all buffer indices compile-time).
// ---------------------------------------------------------------------------
#define WAVES 4
#define ITERS 8
#define EDGES_PER_BLOCK (WAVES * 32 * ITERS)   // 1024

__global__ __launch_bounds__(256) void edge_mfma32p_kernel(
        const unsigned short* __restrict__ Htab,
        const unsigned short* __restrict__ Btab,
        const int* __restrict__ ei,
        const float* __restrict__ W2, const float* __restrict__ b2,
        const float* __restrict__ W3, const float* __restrict__ b3,
        float* __restrict__ out, int nE) {
    const int tid = threadIdx.x;
    const int w  = tid >> 6;       // wave id 0..3
    const int l  = tid & 63;       // lane
    const int el = l & 31;         // edge slot (B col / D col)
    const int hi = l >> 5;         // k-group / n-group select

    // --- Static A-frags: W2^T in bf16 (once per block) ---
    s16x8 Af[4];
#pragma unroll
    for (int f = 0; f < 4; ++f) {
        s16x8 a;
#pragma unroll
        for (int i = 0; i < 8; ++i) {
            float v = W2[(f * 16 + hi * 8 + i) * 32 + el];
            a[i] = (short)((__float_as_uint(v) + 0x8000u) >> 16);
        }
        Af[f] = a;
    }
    // --- Per-lane epilogue constants: n(reg) = (reg&3) + 8*(reg>>2) + 4*hi ---
    float b2i[16], w3v[16];
#pragma unroll
    for (int r = 0; r < 16; ++r) {
        int n = (r & 3) + 8 * (r >> 2) + 4 * hi;
        b2i[r] = b2[n];
        w3v[r] = W3[n];
    }
    const float b3v = b3[0];

    const int base0 = blockIdx.x * EDGES_PER_BLOCK + w * 32;

    // --- Prologue: all ei loads for all ITERS (coalesced, issued together) ---
    int sv[ITERS], dv[ITERS];
#pragma unroll
    for (int i = 0; i < ITERS; ++i) {
        int e  = base0 + i * (WAVES * 32) + el;
        int ec = e < nE ? e : (nE - 1);
        sv[i] = ei[ec];
        dv[i] = ei[nE + ec];
    }

    // gather one edge's table halves (4 x 16B from each table)
    auto GATHER = [&](int s, int d, uint4* hq, uint4* bq) {
        const unsigned short* ph = Htab + ((size_t)s << 6) + (hi << 3);
        const unsigned short* pb = Btab + ((size_t)d << 6) + (hi << 3);
        hq[0] = *reinterpret_cast<const uint4*>(ph +  0);
        hq[1] = *reinterpret_cast<const uint4*>(ph + 16);
        hq[2] = *reinterpret_cast<const uint4*>(ph + 32);
        hq[3] = *reinterpret_cast<const uint4*>(ph + 48);
        bq[0] = *reinterpret_cast<const uint4*>(pb +  0);
        bq[1] = *reinterpret_cast<const uint4*>(pb + 16);
        bq[2] = *reinterpret_cast<const uint4*>(pb + 32);
        bq[3] = *reinterpret_cast<const uint4*>(pb + 48);
    };

    // compute + store one iteration from gathered buffers
    auto COMPUTE = [&](const uint4* hqs, const uint4* bqs, int it, int s, int d) {
        f32x16 acc;
#pragma unroll
        for (int r = 0; r < 16; ++r) acc[r] = b2i[r];

#pragma unroll
        for (int f = 0; f < 4; ++f) {
            unsigned int hu[4] = {hqs[f].x, hqs[f].y, hqs[f].z, hqs[f].w};
            unsigned int bu[4] = {bqs[f].x, bqs[f].y, bqs[f].z, bqs[f].w};
            union { unsigned int u[4]; s16x8 v; } bf;
#pragma unroll
            for (int q = 0; q < 4; ++q) {
                float lo = __uint_as_float(hu[q] << 16) +
                           __uint_as_float(bu[q] << 16);
                float h2 = __uint_as_float(hu[q] & 0xffff0000u) +
                           __uint_as_float(bu[q] & 0xffff0000u);
                lo = fmaxf(lo, 0.0f);
                h2 = fmaxf(h2, 0.0f);
                bf.u[q] = __builtin_amdgcn_perm(__float_as_uint(h2),
                                                __float_as_uint(lo),
                                                0x07060302u);
            }
            acc = __builtin_amdgcn_mfma_f32_32x32x16_bf16(Af[f], bf.v, acc, 0, 0, 0);
        }

        float v = 0.0f;
#pragma unroll
        for (int r = 0; r < 16; ++r)
            v = fmaf(fmaxf(acc[r], 0.0f), w3v[r], v);
        v += __shfl_xor(v, 32);

        float p = 1.0f / (1.0f + __expf(-(v + b3v)));

        int e = base0 + it * (WAVES * 32) + el;
        if (e < nE) {
            if (hi == 0) {
                out[e] = p;                              // probs
                out[nE + e] = (float)s;                  // edge_index row 0
            } else {
                out[(size_t)2 * nE + e] = (float)d;      // edge_index row 1
            }
        }
    };

    // --- Double-buffered pipeline (fully unrolled, static buffer names) ---
    uint4 hA[4], bA[4], hB[4], bB[4];
    GATHER(sv[0], dv[0], hA, bA);
#pragma unroll
    for (int it = 0; it < ITERS; it += 2) {
        if (it + 1 < ITERS) GATHER(sv[it + 1], dv[it + 1], hB, bB);
        COMPUTE(hA, bA, it, sv[it], dv[it]);
        if (it + 2 < ITERS) GATHER(sv[it + 2], dv[it + 2], hA, bA);
        if (it + 1 < ITERS) COMPUTE(hB, bB, it + 1, sv[it + 1], dv[it + 1]);
    }
}

// ---------------------------------------------------------------------------
// Fallback: per-edge full MLP (no workspace), f32 output.
// ---------------------------------------------------------------------------
__global__ __launch_bounds__(256) void edge_mlp_naive_kernel(
        const float* __restrict__ emb, const int* __restrict__ ei,
        const float* __restrict__ W1, const float* __restrict__ b1,
        const float* __restrict__ W2, const float* __restrict__ b2,
        const float* __restrict__ W3, const float* __restrict__ b3,
        float* __restrict__ out, int nE) {
    __shared__ __align__(16) float sW1[32 * 64];
    __shared__ __align__(16) float sW2[64 * 32];
    __shared__ float sW3[32];
    __shared__ float sB1[64];
    __shared__ float sB2[32];
    __shared__ float sB3;
    for (int i = threadIdx.x; i < 2048; i += 256) {
        sW1[i] = W1[i];
        sW2[i] = W2[i];
    }
    if (threadIdx.x < 64) sB1[threadIdx.x] = b1[threadIdx.x];
    if (threadIdx.x < 32) {
        sW3[threadIdx.x] = W3[threadIdx.x];
        sB2[threadIdx.x] = b2[threadIdx.x];
    }
    if (threadIdx.x == 0) sB3 = b3[0];
    __syncthreads();

    int e = blockIdx.x * 256 + threadIdx.x;
    if (e >= nE) return;

    int s = ei[e];
    int d = ei[nE + e];

    float f[32];
    const float4* ps = reinterpret_cast<const float4*>(emb + (size_t)s * NEMB);
    const float4* pd = reinterpret_cast<const float4*>(emb + (size_t)d * NEMB);
#pragma unroll
    for (int q = 0; q < 4; ++q) {
        float4 v = ps[q];
        f[4 * q + 0] = v.x; f[4 * q + 1] = v.y; f[4 * q + 2] = v.z; f[4 * q + 3] = v.w;
    }
#pragma unroll
    for (int q = 0; q < 4; ++q) {
        float4 v = pd[q];
        f[16 + 4 * q + 0] = v.x; f[16 + 4 * q + 1] = v.y;
        f[16 + 4 * q + 2] = v.z; f[16 + 4 * q + 3] = v.w;
    }

    float h1[64];
#pragma unroll
    for (int j = 0; j < 64; j += 4) {
        float a0 = sB1[j + 0], a1 = sB1[j + 1], a2 = sB1[j + 2], a3 = sB1[j + 3];
#pragma unroll
        for (int k = 0; k < 32; ++k) {
            float4 wv = *reinterpret_cast<const float4*>(sW1 + k * 64 + j);
            a0 = fmaf(f[k], wv.x, a0);
            a1 = fmaf(f[k], wv.y, a1);
            a2 = fmaf(f[k], wv.z, a2);
            a3 = fmaf(f[k], wv.w, a3);
        }
        h1[j + 0] = fmaxf(a0, 0.0f);
        h1[j + 1] = fmaxf(a1, 0.0f);
        h1[j + 2] = fmaxf(a2, 0.0f);
        h1[j + 3] = fmaxf(a3, 0.0f);
    }

    float acc = sB3;
#pragma unroll
    for (int j = 0; j < 32; j += 4) {
        float a0 = sB2[j + 0], a1 = sB2[j + 1], a2 = sB2[j + 2], a3 = sB2[j + 3];
#pragma unroll
        for (int k = 0; k < 64; ++k) {
            float4 wv = *reinterpret_cast<const float4*>(sW2 + k * 32 + j);
            a0 = fmaf(h1[k], wv.x, a0);
            a1 = fmaf(h1[k], wv.y, a1);
            a2 = fmaf(h1[k], wv.z, a2);
            a3 = fmaf(h1[k], wv.w, a3);
        }
        acc = fmaf(fmaxf(a0, 0.0f), sW3[j + 0], acc);
        acc = fmaf(fmaxf(a1, 0.0f), sW3[j + 1], acc);
        acc = fmaf(fmaxf(a2, 0.0f), sW3[j + 2], acc);
        acc = fmaf(fmaxf(a3, 0.0f), sW3[j + 3], acc);
    }

    out[e] = 1.0f / (1.0f + __expf(-acc));
}

// ---------------------------------------------------------------------------
// Kernel A (fallback path only): edge_index (int32) -> f32 copy into out[E..3E)
// ---------------------------------------------------------------------------
__global__ __launch_bounds__(256) void edge_idx_copy_kernel(
        const int* __restrict__ ei, float* __restrict__ out, int n) {
    int i = (blockIdx.x * 256 + threadIdx.x) * 4;
    if (i + 4 <= n) {
        int4 a = *reinterpret_cast<const int4*>(ei + i);
        float4 r = make_float4((float)a.x, (float)a.y, (float)a.z, (float)a.w);
        *reinterpret_cast<float4*>(out + i) = r;
    } else {
        for (; i < n; ++i) out[i] = (float)ei[i];
    }
}

extern "C" void kernel_launch(void* const* d_in, const int* in_sizes, int n_in,
                              void* d_out, int out_size, void* d_ws, size_t ws_size,
                              hipStream_t stream) {
    const float* emb = (const float*)d_in[0];
    const int*   ei  = (const int*)d_in[1];
    const float* W1  = (const float*)d_in[2];
    const float* b1  = (const float*)d_in[3];
    const float* W2  = (const float*)d_in[4];
    const float* b2  = (const float*)d_in[5];
    const float* W3  = (const float*)d_in[6];
    const float* b3  = (const float*)d_in[7];

    const int nNodes = in_sizes[0] / NEMB;   // 100000
    const int n2E    = in_sizes[1];          // 2 * E
    const int nE     = n2E / 2;              // E

    float* out = (float*)d_out;  // f32: [E probs][2E edge indices]

    const size_t tbl_bytes = (size_t)nNodes * 64 * sizeof(unsigned short);  // 12.8 MB
    const bool use_ws = (ws_size >= 2 * tbl_bytes);

    if (use_ws) {
        unsigned int* Htab = (unsigned int*)d_ws;
        unsigned int* Btab = Htab + (size_t)nNodes * 32;

        precompute_h1_kernel<<<(nNodes + 255) / 256, 256, 0, stream>>>(
            emb, W1, b1, Htab, Btab, nNodes);

        edge_mfma32p_kernel<<<(nE + EDGES_PER_BLOCK - 1) / EDGES_PER_BLOCK, 256, 0,
                              stream>>>(
            (const unsigned short*)Htab, (const unsigned short*)Btab, ei,
            W2, b2, W3, b3, out, nE);
        // edge-index copy fused into edge_mfma32p_kernel
    } else {
        edge_mlp_naive_kernel<<<(nE + 255) / 256, 256, 0, stream>>>(
            emb, ei, W1, b1, W2, b2, W3, b3, out, nE);
        edge_idx_copy_kernel<<<((n2E + 3) / 4 + 255) / 256, 256, 0, stream>>>(
            ei, out + nE, n2E);
    }
}

// Round 7
// 95.695 us; speedup vs baseline: 2.1624x; 1.8895x over previous
//
#include <hip/hip_runtime.h>
#include <hip/hip_bf16.h>

#define NEMB 16

typedef short s16x8 __attribute__((ext_vector_type(8)));
typedef float f32x16 __attribute__((ext_vector_type(16)));

__device__ __forceinline__ unsigned int pack_bf16x2_rnd(float lo, float hi) {
    unsigned int ul = __float_as_uint(lo);
    unsigned int uh = __float_as_uint(hi);
    return ((ul + 0x8000u) >> 16) | ((uh + 0x8000u) & 0xffff0000u);
}
// truncate-pack [bf16(lo), bf16(hi)] into one u32 with a single v_perm
__device__ __forceinline__ unsigned int pack_bf16x2_trunc(float lo, float hi) {
    return __builtin_amdgcn_perm(__float_as_uint(hi), __float_as_uint(lo),
                                 0x07060302u);
}

// ---------------------------------------------------------------------------
// Kernel P: emb f32 -> bf16 table (3.2 MB, L2-resident). 8 floats/thread.
// ---------------------------------------------------------------------------
__global__ __launch_bounds__(256) void emb_to_bf16_kernel(
        const float* __restrict__ emb, unsigned int* __restrict__ embT,
        int nWords) {  // nWords = nNodes*8 (one word = 2 bf16)
    int i = (blockIdx.x * 256 + threadIdx.x) * 4;
    if (i + 4 <= nWords) {
        float4 a = *reinterpret_cast<const float4*>(emb + 2 * i);
        float4 b = *reinterpret_cast<const float4*>(emb + 2 * i + 4);
        uint4 r;
        r.x = pack_bf16x2_rnd(a.x, a.y);
        r.y = pack_bf16x2_rnd(a.z, a.w);
        r.z = pack_bf16x2_rnd(b.x, b.y);
        r.w = pack_bf16x2_rnd(b.z, b.w);
        *reinterpret_cast<uint4*>(embT + i) = r;
    } else {
        for (; i < nWords; ++i)
            embT[i] = pack_bf16x2_rnd(emb[2 * i], emb[2 * i + 1]);
    }
}

// ---------------------------------------------------------------------------
// Kernel E: fully fused 3-layer MLP, 32 edges/wave-iter, both GEMMs on MFMA.
//   Layer1: D[j][e] = sum_k W1T[j][k]*feats[k][e] + b1[j]  (2 j-tiles x 2 k-halves)
//     B-frag (k-half 0) = emb[s_e][hi*8..+7]  -> ONE 16B gather per lane
//     B-frag (k-half 1) = emb[d_e][hi*8..+7]  -> ONE 16B gather per lane
//   Repack: lane pair (l, l^32) exchanges 4-elem quads (8x shfl_xor(32))
//     to form layer-2 B-frags h1[e][f*16+hi*8..+7] (relu + trunc-pack).
//   Layer2: D[n][e] = W2T . h1 + b2 (C-init);  Layer3: 16 fma + 1 shfl_xor.
//   Edge-index f32 copy fused.
// ---------------------------------------------------------------------------
#define WAVES 4
#define ITERS 8
#define EDGES_PER_BLOCK (WAVES * 32 * ITERS)   // 1024

__global__ __launch_bounds__(256) void edge_fused_kernel(
        const unsigned short* __restrict__ embT,
        const int* __restrict__ ei,
        const float* __restrict__ W1, const float* __restrict__ b1,
        const float* __restrict__ W2, const float* __restrict__ b2,
        const float* __restrict__ W3, const float* __restrict__ b3,
        float* __restrict__ out, int nE) {
    const int tid = threadIdx.x;
    const int w  = tid >> 6;       // wave 0..3
    const int l  = tid & 63;
    const int el = l & 31;         // edge slot / matrix row m / D col
    const int hi = l >> 5;         // k/n half select

    // ---- Layer-1 A-frags: A1[jt][kh][i] = W1[kh*16 + hi*8 + i][jt*32 + el] ----
    s16x8 A1[2][2];
#pragma unroll
    for (int jt = 0; jt < 2; ++jt)
#pragma unroll
        for (int kh = 0; kh < 2; ++kh) {
            s16x8 a;
#pragma unroll
            for (int i = 0; i < 8; ++i) {
                float v = W1[(kh * 16 + hi * 8 + i) * 64 + jt * 32 + el];
                a[i] = (short)((__float_as_uint(v) + 0x8000u) >> 16);
            }
            A1[jt][kh] = a;
        }
    // ---- Layer-2 A-frags: A2[f][i] = W2[f*16 + hi*8 + i][el] ----
    s16x8 A2[4];
#pragma unroll
    for (int f = 0; f < 4; ++f) {
        s16x8 a;
#pragma unroll
        for (int i = 0; i < 8; ++i) {
            float v = W2[(f * 16 + hi * 8 + i) * 32 + el];
            a[i] = (short)((__float_as_uint(v) + 0x8000u) >> 16);
        }
        A2[f] = a;
    }
    // ---- per-lane C-init / epilogue vectors: n(r) = (r&3)+8*(r>>2)+4*hi ----
    f32x16 b1v0, b1v1, b2v;
    float w3v[16];
#pragma unroll
    for (int r = 0; r < 16; ++r) {
        int n = (r & 3) + 8 * (r >> 2) + 4 * hi;
        b1v0[r] = b1[n];
        b1v1[r] = b1[32 + n];
        b2v[r]  = b2[n];
        w3v[r]  = W3[n];
    }
    const float b3v = b3[0];

    const int base0 = blockIdx.x * EDGES_PER_BLOCK + w * 32;

    // ---- prologue: all ei loads (coalesced, issued together) ----
    int sv[ITERS], dv[ITERS];
#pragma unroll
    for (int i = 0; i < ITERS; ++i) {
        int e  = base0 + i * (WAVES * 32) + el;
        int ec = e < nE ? e : (nE - 1);
        sv[i] = ei[ec];
        dv[i] = ei[nE + ec];
    }

    auto GATHER = [&](int s, int d, uint4& es, uint4& ed) {
        es = *reinterpret_cast<const uint4*>(embT + ((size_t)s << 4) + (hi << 3));
        ed = *reinterpret_cast<const uint4*>(embT + ((size_t)d << 4) + (hi << 3));
    };

    auto COMPUTE = [&](uint4 esq, uint4 edq, int it, int s, int d) {
        union { uint4 q; s16x8 v; } es, edr;
        es.q = esq; edr.q = edq;

        // ---- layer 1: two j-tiles, K=32 over [emb_s; emb_d] ----
        f32x16 a0 = __builtin_amdgcn_mfma_f32_32x32x16_bf16(A1[0][0], es.v,  b1v0, 0, 0, 0);
        a0        = __builtin_amdgcn_mfma_f32_32x32x16_bf16(A1[0][1], edr.v, a0,   0, 0, 0);
        f32x16 a1 = __builtin_amdgcn_mfma_f32_32x32x16_bf16(A1[1][0], es.v,  b1v1, 0, 0, 0);
        a1        = __builtin_amdgcn_mfma_f32_32x32x16_bf16(A1[1][1], edr.v, a1,   0, 0, 0);

        // ---- relu + pack each 4-elem quad into 2 bf16x2 words ----
        // quad q of tile t covers j = t*32 + 8*q + 4*hi + (0..3)
        unsigned int PW[2][4][2];
#pragma unroll
        for (int q = 0; q < 4; ++q) {
            PW[0][q][0] = pack_bf16x2_trunc(fmaxf(a0[4 * q + 0], 0.f), fmaxf(a0[4 * q + 1], 0.f));
            PW[0][q][1] = pack_bf16x2_trunc(fmaxf(a0[4 * q + 2], 0.f), fmaxf(a0[4 * q + 3], 0.f));
            PW[1][q][0] = pack_bf16x2_trunc(fmaxf(a1[4 * q + 0], 0.f), fmaxf(a1[4 * q + 1], 0.f));
            PW[1][q][1] = pack_bf16x2_trunc(fmaxf(a1[4 * q + 2], 0.f), fmaxf(a1[4 * q + 3], 0.f));
        }

        // ---- exchange quads with lane^32, assemble layer-2 B-frags, MFMA ----
        f32x16 acc;
#pragma unroll
        for (int f = 0; f < 4; ++f) {
            const int t = f >> 1, m = f & 1;
            // lane h keeps quad 2m+h, sends quad 2m+(h^1), receives partner's 2m+h
            unsigned int keep0 = hi ? PW[t][2 * m + 1][0] : PW[t][2 * m][0];
            unsigned int keep1 = hi ? PW[t][2 * m + 1][1] : PW[t][2 * m][1];
            unsigned int send0 = hi ? PW[t][2 * m][0]     : PW[t][2 * m + 1][0];
            unsigned int send1 = hi ? PW[t][2 * m][1]     : PW[t][2 * m + 1][1];
            unsigned int recv0 = (unsigned int)__shfl_xor((int)send0, 32);
            unsigned int recv1 = (unsigned int)__shfl_xor((int)send1, 32);
            union { unsigned int u[4]; s16x8 v; } bf;
            bf.u[0] = hi ? recv0 : keep0;   // elements i=0,1  (j = f*16+8h+0,1)
            bf.u[1] = hi ? recv1 : keep1;   // i=2,3
            bf.u[2] = hi ? keep0 : recv0;   // i=4,5
            bf.u[3] = hi ? keep1 : recv1;   // i=6,7
            if (f == 0)
                acc = __builtin_amdgcn_mfma_f32_32x32x16_bf16(A2[f], bf.v, b2v, 0, 0, 0);
            else
                acc = __builtin_amdgcn_mfma_f32_32x32x16_bf16(A2[f], bf.v, acc, 0, 0, 0);
        }

        // ---- layer 3 + epilogue ----
        float v = 0.0f;
#pragma unroll
        for (int r = 0; r < 16; ++r)
            v = fmaf(fmaxf(acc[r], 0.0f), w3v[r], v);
        v += __shfl_xor(v, 32);

        float p = 1.0f / (1.0f + __expf(-(v + b3v)));

        int e = base0 + it * (WAVES * 32) + el;
        if (e < nE) {
            if (hi == 0) {
                out[e] = p;                          // probs
                out[nE + e] = (float)s;              // edge_index row 0
            } else {
                out[(size_t)2 * nE + e] = (float)d;  // edge_index row 1
            }
        }
    };

    // ---- double-buffered pipeline (static buffer names) ----
    uint4 esA, edA, esB, edB;
    GATHER(sv[0], dv[0], esA, edA);
#pragma unroll
    for (int it = 0; it < ITERS; it += 2) {
        if (it + 1 < ITERS) GATHER(sv[it + 1], dv[it + 1], esB, edB);
        COMPUTE(esA, edA, it, sv[it], dv[it]);
        if (it + 2 < ITERS) GATHER(sv[it + 2], dv[it + 2], esA, edA);
        if (it + 1 < ITERS) COMPUTE(esB, edB, it + 1, sv[it + 1], dv[it + 1]);
    }
}

// ---------------------------------------------------------------------------
// Fallback: per-edge full MLP (no workspace), f32 output.
// ---------------------------------------------------------------------------
__global__ __launch_bounds__(256) void edge_mlp_naive_kernel(
        const float* __restrict__ emb, const int* __restrict__ ei,
        const float* __restrict__ W1, const float* __restrict__ b1,
        const float* __restrict__ W2, const float* __restrict__ b2,
        const float* __restrict__ W3, const float* __restrict__ b3,
        float* __restrict__ out, int nE) {
    __shared__ __align__(16) float sW1[32 * 64];
    __shared__ __align__(16) float sW2[64 * 32];
    __shared__ float sW3[32];
    __shared__ float sB1[64];
    __shared__ float sB2[32];
    __shared__ float sB3;
    for (int i = threadIdx.x; i < 2048; i += 256) {
        sW1[i] = W1[i];
        sW2[i] = W2[i];
    }
    if (threadIdx.x < 64) sB1[threadIdx.x] = b1[threadIdx.x];
    if (threadIdx.x < 32) {
        sW3[threadIdx.x] = W3[threadIdx.x];
        sB2[threadIdx.x] = b2[threadIdx.x];
    }
    if (threadIdx.x == 0) sB3 = b3[0];
    __syncthreads();

    int e = blockIdx.x * 256 + threadIdx.x;
    if (e >= nE) return;

    int s = ei[e];
    int d = ei[nE + e];

    float f[32];
    const float4* ps = reinterpret_cast<const float4*>(emb + (size_t)s * NEMB);
    const float4* pd = reinterpret_cast<const float4*>(emb + (size_t)d * NEMB);
#pragma unroll
    for (int q = 0; q < 4; ++q) {
        float4 v = ps[q];
        f[4 * q + 0] = v.x; f[4 * q + 1] = v.y; f[4 * q + 2] = v.z; f[4 * q + 3] = v.w;
    }
#pragma unroll
    for (int q = 0; q < 4; ++q) {
        float4 v = pd[q];
        f[16 + 4 * q + 0] = v.x; f[16 + 4 * q + 1] = v.y;
        f[16 + 4 * q + 2] = v.z; f[16 + 4 * q + 3] = v.w;
    }

    float h1[64];
#pragma unroll
    for (int j = 0; j < 64; j += 4) {
        float a0 = sB1[j + 0], a1 = sB1[j + 1], a2 = sB1[j + 2], a3 = sB1[j + 3];
#pragma unroll
        for (int k = 0; k < 32; ++k) {
            float4 wv = *reinterpret_cast<const float4*>(sW1 + k * 64 + j);
            a0 = fmaf(f[k], wv.x, a0);
            a1 = fmaf(f[k], wv.y, a1);
            a2 = fmaf(f[k], wv.z, a2);
            a3 = fmaf(f[k], wv.w, a3);
        }
        h1[j + 0] = fmaxf(a0, 0.0f);
        h1[j + 1] = fmaxf(a1, 0.0f);
        h1[j + 2] = fmaxf(a2, 0.0f);
        h1[j + 3] = fmaxf(a3, 0.0f);
    }

    float acc = sB3;
#pragma unroll
    for (int j = 0; j < 32; j += 4) {
        float a0 = sB2[j + 0], a1 = sB2[j + 1], a2 = sB2[j + 2], a3 = sB2[j + 3];
#pragma unroll
        for (int k = 0; k < 64; ++k) {
            float4 wv = *reinterpret_cast<const float4*>(sW2 + k * 32 + j);
            a0 = fmaf(h1[k], wv.x, a0);
            a1 = fmaf(h1[k], wv.y, a1);
            a2 = fmaf(h1[k], wv.z, a2);
            a3 = fmaf(h1[k], wv.w, a3);
        }
        acc = fmaf(fmaxf(a0, 0.0f), sW3[j + 0], acc);
        acc = fmaf(fmaxf(a1, 0.0f), sW3[j + 1], acc);
        acc = fmaf(fmaxf(a2, 0.0f), sW3[j + 2], acc);
        acc = fmaf(fmaxf(a3, 0.0f), sW3[j + 3], acc);
    }

    out[e] = 1.0f / (1.0f + __expf(-acc));
}

__global__ __launch_bounds__(256) void edge_idx_copy_kernel(
        const int* __restrict__ ei, float* __restrict__ out, int n) {
    int i = (blockIdx.x * 256 + threadIdx.x) * 4;
    if (i + 4 <= n) {
        int4 a = *reinterpret_cast<const int4*>(ei + i);
        float4 r = make_float4((float)a.x, (float)a.y, (float)a.z, (float)a.w);
        *reinterpret_cast<float4*>(out + i) = r;
    } else {
        for (; i < n; ++i) out[i] = (float)ei[i];
    }
}

extern "C" void kernel_launch(void* const* d_in, const int* in_sizes, int n_in,
                              void* d_out, int out_size, void* d_ws, size_t ws_size,
                              hipStream_t stream) {
    const float* emb = (const float*)d_in[0];
    const int*   ei  = (const int*)d_in[1];
    const float* W1  = (const float*)d_in[2];
    const float* b1  = (const float*)d_in[3];
    const float* W2  = (const float*)d_in[4];
    const float* b2  = (const float*)d_in[5];
    const float* W3  = (const float*)d_in[6];
    const float* b3  = (const float*)d_in[7];

    const int nNodes = in_sizes[0] / NEMB;   // 100000
    const int n2E    = in_sizes[1];          // 2 * E
    const int nE     = n2E / 2;              // E

    float* out = (float*)d_out;  // f32: [E probs][2E edge indices]

    const size_t tbl_bytes = (size_t)nNodes * NEMB * sizeof(unsigned short);  // 3.2 MB
    const bool use_ws = (ws_size >= tbl_bytes);

    if (use_ws) {
        unsigned int* embT = (unsigned int*)d_ws;
        const int nWords = nNodes * 8;
        emb_to_bf16_kernel<<<(nWords / 4 + 255) / 256, 256, 0, stream>>>(
            emb, embT, nWords);

        edge_fused_kernel<<<(nE + EDGES_PER_BLOCK - 1) / EDGES_PER_BLOCK, 256, 0,
                            stream>>>(
            (const unsigned short*)embT, ei, W1, b1, W2, b2, W3, b3, out, nE);
        // edge-index copy fused into edge_fused_kernel
    } else {
        edge_mlp_naive_kernel<<<(nE + 255) / 256, 256, 0, stream>>>(
            emb, ei, W1, b1, W2, b2, W3, b3, out, nE);
        edge_idx_copy_kernel<<<((n2E + 3) / 4 + 255) / 256, 256, 0, stream>>>(
            ei, out + nE, n2E);
    }
}

// Round 8
// 86.979 us; speedup vs baseline: 2.3790x; 1.1002x over previous
//
#include <hip/hip_runtime.h>
#include <hip/hip_bf16.h>

#define NEMB 16

typedef short s16x8 __attribute__((ext_vector_type(8)));
typedef float f32x16 __attribute__((ext_vector_type(16)));

__device__ __forceinline__ unsigned int pack_bf16x2_rnd(float lo, float hi) {
    unsigned int ul = __float_as_uint(lo);
    unsigned int uh = __float_as_uint(hi);
    return ((ul + 0x8000u) >> 16) | ((uh + 0x8000u) & 0xffff0000u);
}
// truncate-pack [bf16(lo), bf16(hi)] into one u32 with a single v_perm
__device__ __forceinline__ unsigned int pack_bf16x2_trunc(float lo, float hi) {
    return __builtin_amdgcn_perm(__float_as_uint(hi), __float_as_uint(lo),
                                 0x07060302u);
}

// ---------------------------------------------------------------------------
// Kernel P: emb f32 -> bf16 table (3.2 MB, L2-resident). 8 floats/thread.
// ---------------------------------------------------------------------------
__global__ __launch_bounds__(256) void emb_to_bf16_kernel(
        const float* __restrict__ emb, unsigned int* __restrict__ embT,
        int nWords) {  // nWords = nNodes*8 (one word = 2 bf16)
    int i = (blockIdx.x * 256 + threadIdx.x) * 4;
    if (i + 4 <= nWords) {
        float4 a = *reinterpret_cast<const float4*>(emb + 2 * i);
        float4 b = *reinterpret_cast<const float4*>(emb + 2 * i + 4);
        uint4 r;
        r.x = pack_bf16x2_rnd(a.x, a.y);
        r.y = pack_bf16x2_rnd(a.z, a.w);
        r.z = pack_bf16x2_rnd(b.x, b.y);
        r.w = pack_bf16x2_rnd(b.z, b.w);
        *reinterpret_cast<uint4*>(embT + i) = r;
    } else {
        for (; i < nWords; ++i)
            embT[i] = pack_bf16x2_rnd(emb[2 * i], emb[2 * i + 1]);
    }
}

// ---------------------------------------------------------------------------
// Kernel E: fully fused 3-layer MLP, 32 edges/wave-iter, both GEMMs on MFMA.
// Cross-lane exchange via v_permlane32_swap_b32 (VALU pipe, no LDS):
//   per f: X=pack(quad 2m), Y=pack(quad 2m+1); swap(Y,X) leaves every lane's
//   layer-2 B-frag uniformly {x0,x1,y0,y1} (no cndmask in either half).
// Epilogue cross-half reduce: one swap + uniform add.
// ---------------------------------------------------------------------------
#define WAVES 4
#define ITERS 8
#define EDGES_PER_BLOCK (WAVES * 32 * ITERS)   // 1024

__global__ __launch_bounds__(256) void edge_fused2_kernel(
        const unsigned short* __restrict__ embT,
        const int* __restrict__ ei,
        const float* __restrict__ W1, const float* __restrict__ b1,
        const float* __restrict__ W2, const float* __restrict__ b2,
        const float* __restrict__ W3, const float* __restrict__ b3,
        float* __restrict__ out, int nE) {
    const int tid = threadIdx.x;
    const int w  = tid >> 6;       // wave 0..3
    const int l  = tid & 63;
    const int el = l & 31;         // edge slot / matrix row m / D col
    const int hi = l >> 5;         // k/n half select

    // ---- Layer-1 A-frags: A1[jt][kh][i] = W1[kh*16 + hi*8 + i][jt*32 + el] ----
    s16x8 A1[2][2];
#pragma unroll
    for (int jt = 0; jt < 2; ++jt)
#pragma unroll
        for (int kh = 0; kh < 2; ++kh) {
            s16x8 a;
#pragma unroll
            for (int i = 0; i < 8; ++i) {
                float v = W1[(kh * 16 + hi * 8 + i) * 64 + jt * 32 + el];
                a[i] = (short)((__float_as_uint(v) + 0x8000u) >> 16);
            }
            A1[jt][kh] = a;
        }
    // ---- Layer-2 A-frags: A2[f][i] = W2[f*16 + hi*8 + i][el] ----
    s16x8 A2[4];
#pragma unroll
    for (int f = 0; f < 4; ++f) {
        s16x8 a;
#pragma unroll
        for (int i = 0; i < 8; ++i) {
            float v = W2[(f * 16 + hi * 8 + i) * 32 + el];
            a[i] = (short)((__float_as_uint(v) + 0x8000u) >> 16);
        }
        A2[f] = a;
    }
    // ---- per-lane C-init / epilogue vectors: n(r) = (r&3)+8*(r>>2)+4*hi ----
    f32x16 b1v0, b1v1, b2v;
    float w3v[16];
#pragma unroll
    for (int r = 0; r < 16; ++r) {
        int n = (r & 3) + 8 * (r >> 2) + 4 * hi;
        b1v0[r] = b1[n];
        b1v1[r] = b1[32 + n];
        b2v[r]  = b2[n];
        w3v[r]  = W3[n];
    }
    const float b3v = b3[0];

    const int base0 = blockIdx.x * EDGES_PER_BLOCK + w * 32;

    // ---- prologue: all ei loads (coalesced, issued together) ----
    int sv[ITERS], dv[ITERS];
#pragma unroll
    for (int i = 0; i < ITERS; ++i) {
        int e  = base0 + i * (WAVES * 32) + el;
        int ec = e < nE ? e : (nE - 1);
        sv[i] = ei[ec];
        dv[i] = ei[nE + ec];
    }

    auto GATHER = [&](int s, int d, uint4& es, uint4& ed) {
        es = *reinterpret_cast<const uint4*>(embT + ((size_t)s << 4) + (hi << 3));
        ed = *reinterpret_cast<const uint4*>(embT + ((size_t)d << 4) + (hi << 3));
    };

    auto COMPUTE = [&](uint4 esq, uint4 edq, int it, int s, int d) {
        union { uint4 q; s16x8 v; } es, edr;
        es.q = esq; edr.q = edq;

        // ---- layer 1: two j-tiles, K=32 over [emb_s; emb_d] ----
        f32x16 a0 = __builtin_amdgcn_mfma_f32_32x32x16_bf16(A1[0][0], es.v,  b1v0, 0, 0, 0);
        a0        = __builtin_amdgcn_mfma_f32_32x32x16_bf16(A1[0][1], edr.v, a0,   0, 0, 0);
        f32x16 a1 = __builtin_amdgcn_mfma_f32_32x32x16_bf16(A1[1][0], es.v,  b1v1, 0, 0, 0);
        a1        = __builtin_amdgcn_mfma_f32_32x32x16_bf16(A1[1][1], edr.v, a1,   0, 0, 0);

        // ---- relu + pack + permlane32_swap -> layer-2 B-frags -> MFMA ----
        f32x16 acc;
#pragma unroll
        for (int f = 0; f < 4; ++f) {
            const int m = f & 1;
            const f32x16& at = (f >> 1) ? a1 : a0;
            // quad 2m   (X): at[8m+0..3];  quad 2m+1 (Y): at[8m+4..7]
            unsigned int x0 = pack_bf16x2_trunc(fmaxf(at[8 * m + 0], 0.f),
                                                fmaxf(at[8 * m + 1], 0.f));
            unsigned int x1 = pack_bf16x2_trunc(fmaxf(at[8 * m + 2], 0.f),
                                                fmaxf(at[8 * m + 3], 0.f));
            unsigned int y0 = pack_bf16x2_trunc(fmaxf(at[8 * m + 4], 0.f),
                                                fmaxf(at[8 * m + 5], 0.f));
            unsigned int y1 = pack_bf16x2_trunc(fmaxf(at[8 * m + 6], 0.f),
                                                fmaxf(at[8 * m + 7], 0.f));
            // swap(dst=Y, src=X): lanes<32 get partner X in Y; lanes>=32 get
            // partner Y in X. Resulting frag {x0,x1,y0,y1} is correct for BOTH
            // halves -- no selects.
            asm("v_permlane32_swap_b32 %0, %1" : "+v"(y0), "+v"(x0));
            asm("v_permlane32_swap_b32 %0, %1" : "+v"(y1), "+v"(x1));
            union { unsigned int u[4]; s16x8 v; } bf;
            bf.u[0] = x0; bf.u[1] = x1; bf.u[2] = y0; bf.u[3] = y1;
            if (f == 0)
                acc = __builtin_amdgcn_mfma_f32_32x32x16_bf16(A2[f], bf.v, b2v, 0, 0, 0);
            else
                acc = __builtin_amdgcn_mfma_f32_32x32x16_bf16(A2[f], bf.v, acc, 0, 0, 0);
        }

        // ---- layer 3 + epilogue ----
        float v = 0.0f;
#pragma unroll
        for (int r = 0; r < 16; ++r)
            v = fmaf(fmaxf(acc[r], 0.0f), w3v[r], v);
        // cross-half reduce: one swap + uniform add (no ds_bpermute)
        {
            float va = v, vb = v;
            asm("v_permlane32_swap_b32 %0, %1" : "+v"(vb), "+v"(va));
            v = va + vb;
        }

        float p = 1.0f / (1.0f + __expf(-(v + b3v)));

        int e = base0 + it * (WAVES * 32) + el;
        if (e < nE) {
            if (hi == 0) {
                out[e] = p;                          // probs
                out[nE + e] = (float)s;              // edge_index row 0
            } else {
                out[(size_t)2 * nE + e] = (float)d;  // edge_index row 1
            }
        }
    };

    // ---- double-buffered pipeline (static buffer names) ----
    uint4 esA, edA, esB, edB;
    GATHER(sv[0], dv[0], esA, edA);
#pragma unroll
    for (int it = 0; it < ITERS; it += 2) {
        if (it + 1 < ITERS) GATHER(sv[it + 1], dv[it + 1], esB, edB);
        COMPUTE(esA, edA, it, sv[it], dv[it]);
        if (it + 2 < ITERS) GATHER(sv[it + 2], dv[it + 2], esA, edA);
        if (it + 1 < ITERS) COMPUTE(esB, edB, it + 1, sv[it + 1], dv[it + 1]);
    }
}

// ---------------------------------------------------------------------------
// Fallback: per-edge full MLP (no workspace), f32 output.
// ---------------------------------------------------------------------------
__global__ __launch_bounds__(256) void edge_mlp_naive_kernel(
        const float* __restrict__ emb, const int* __restrict__ ei,
        const float* __restrict__ W1, const float* __restrict__ b1,
        const float* __restrict__ W2, const float* __restrict__ b2,
        const float* __restrict__ W3, const float* __restrict__ b3,
        float* __restrict__ out, int nE) {
    __shared__ __align__(16) float sW1[32 * 64];
    __shared__ __align__(16) float sW2[64 * 32];
    __shared__ float sW3[32];
    __shared__ float sB1[64];
    __shared__ float sB2[32];
    __shared__ float sB3;
    for (int i = threadIdx.x; i < 2048; i += 256) {
        sW1[i] = W1[i];
        sW2[i] = W2[i];
    }
    if (threadIdx.x < 64) sB1[threadIdx.x] = b1[threadIdx.x];
    if (threadIdx.x < 32) {
        sW3[threadIdx.x] = W3[threadIdx.x];
        sB2[threadIdx.x] = b2[threadIdx.x];
    }
    if (threadIdx.x == 0) sB3 = b3[0];
    __syncthreads();

    int e = blockIdx.x * 256 + threadIdx.x;
    if (e >= nE) return;

    int s = ei[e];
    int d = ei[nE + e];

    float f[32];
    const float4* ps = reinterpret_cast<const float4*>(emb + (size_t)s * NEMB);
    const float4* pd = reinterpret_cast<const float4*>(emb + (size_t)d * NEMB);
#pragma unroll
    for (int q = 0; q < 4; ++q) {
        float4 v = ps[q];
        f[4 * q + 0] = v.x; f[4 * q + 1] = v.y; f[4 * q + 2] = v.z; f[4 * q + 3] = v.w;
    }
#pragma unroll
    for (int q = 0; q < 4; ++q) {
        float4 v = pd[q];
        f[16 + 4 * q + 0] = v.x; f[16 + 4 * q + 1] = v.y;
        f[16 + 4 * q + 2] = v.z; f[16 + 4 * q + 3] = v.w;
    }

    float h1[64];
#pragma unroll
    for (int j = 0; j < 64; j += 4) {
        float a0 = sB1[j + 0], a1 = sB1[j + 1], a2 = sB1[j + 2], a3 = sB1[j + 3];
#pragma unroll
        for (int k = 0; k < 32; ++k) {
            float4 wv = *reinterpret_cast<const float4*>(sW1 + k * 64 + j);
            a0 = fmaf(f[k], wv.x, a0);
            a1 = fmaf(f[k], wv.y, a1);
            a2 = fmaf(f[k], wv.z, a2);
            a3 = fmaf(f[k], wv.w, a3);
        }
        h1[j + 0] = fmaxf(a0, 0.0f);
        h1[j + 1] = fmaxf(a1, 0.0f);
        h1[j + 2] = fmaxf(a2, 0.0f);
        h1[j + 3] = fmaxf(a3, 0.0f);
    }

    float acc = sB3;
#pragma unroll
    for (int j = 0; j < 32; j += 4) {
        float a0 = sB2[j + 0], a1 = sB2[j + 1], a2 = sB2[j + 2], a3 = sB2[j + 3];
#pragma unroll
        for (int k = 0; k < 64; ++k) {
            float4 wv = *reinterpret_cast<const float4*>(sW2 + k * 32 + j);
            a0 = fmaf(h1[k], wv.x, a0);
            a1 = fmaf(h1[k], wv.y, a1);
            a2 = fmaf(h1[k], wv.z, a2);
            a3 = fmaf(h1[k], wv.w, a3);
        }
        acc = fmaf(fmaxf(a0, 0.0f), sW3[j + 0], acc);
        acc = fmaf(fmaxf(a1, 0.0f), sW3[j + 1], acc);
        acc = fmaf(fmaxf(a2, 0.0f), sW3[j + 2], acc);
        acc = fmaf(fmaxf(a3, 0.0f), sW3[j + 3], acc);
    }

    out[e] = 1.0f / (1.0f + __expf(-acc));
}

__global__ __launch_bounds__(256) void edge_idx_copy_kernel(
        const int* __restrict__ ei, float* __restrict__ out, int n) {
    int i = (blockIdx.x * 256 + threadIdx.x) * 4;
    if (i + 4 <= n) {
        int4 a = *reinterpret_cast<const int4*>(ei + i);
        float4 r = make_float4((float)a.x, (float)a.y, (float)a.z, (float)a.w);
        *reinterpret_cast<float4*>(out + i) = r;
    } else {
        for (; i < n; ++i) out[i] = (float)ei[i];
    }
}

extern "C" void kernel_launch(void* const* d_in, const int* in_sizes, int n_in,
                              void* d_out, int out_size, void* d_ws, size_t ws_size,
                              hipStream_t stream) {
    const float* emb = (const float*)d_in[0];
    const int*   ei  = (const int*)d_in[1];
    const float* W1  = (const float*)d_in[2];
    const float* b1  = (const float*)d_in[3];
    const float* W2  = (const float*)d_in[4];
    const float* b2  = (const float*)d_in[5];
    const float* W3  = (const float*)d_in[6];
    const float* b3  = (const float*)d_in[7];

    const int nNodes = in_sizes[0] / NEMB;   // 100000
    const int n2E    = in_sizes[1];          // 2 * E
    const int nE     = n2E / 2;              // E

    float* out = (float*)d_out;  // f32: [E probs][2E edge indices]

    const size_t tbl_bytes = (size_t)nNodes * NEMB * sizeof(unsigned short);  // 3.2 MB
    const bool use_ws = (ws_size >= tbl_bytes);

    if (use_ws) {
        unsigned int* embT = (unsigned int*)d_ws;
        const int nWords = nNodes * 8;
        emb_to_bf16_kernel<<<(nWords / 4 + 255) / 256, 256, 0, stream>>>(
            emb, embT, nWords);

        edge_fused2_kernel<<<(nE + EDGES_PER_BLOCK - 1) / EDGES_PER_BLOCK, 256, 0,
                             stream>>>(
            (const unsigned short*)embT, ei, W1, b1, W2, b2, W3, b3, out, nE);
        // edge-index copy fused into edge_fused2_kernel
    } else {
        edge_mlp_naive_kernel<<<(nE + 255) / 256, 256, 0, stream>>>(
            emb, ei, W1, b1, W2, b2, W3, b3, out, nE);
        edge_idx_copy_kernel<<<((n2E + 3) / 4 + 255) / 256, 256, 0, stream>>>(
            ei, out + nE, n2E);
    }
}